// Round 4
// baseline (61.051 us; speedup 1.0000x reference)
//
#include <hip/hip_runtime.h>

// Problem config (fixed by reference): B=64, H=2, N=512, K=64, M=16
constexpr int Bsz = 64;
constexpr int Hn  = 2;
constexpr int Np  = 512;
constexpr int Kk  = 64;
constexpr int Mm  = 16;

constexpr int TS = 68;   // column stride in LDS (16B-aligned, bank-staggered)

#define EPSf      1e-7f
#define MAXN      (1.0f - 1e-5f)
#define ATANH_MAX 6.1030338f     // atanh(1 - 1e-5)
#define HALF_LN2  0.34657359f    // 0.5 * ln(2)

// Index identity (reference's raw reshape (B,K*N,M)->(B,N,K,M)):
//   out[b,h,k'] = epilogue( sum_{k<64} sum_{p<8} tangent(point n=64p+k', theta row k) )
// Per-term (x = exp0(pad(dgm)) + theta_k, only 2 nonzero exp0 comps):
//   u = x0^2+x1^2+c_k, rs = rsqrt(u), r = u*rs, a = atanh(min(r,MAXN))*rs
//   per-lane(k) partial over p: (S0,S1,A); component m>=2 of the sum = sum_k A_k*t[k][m].
// Reduction as a vectorized LDS dot: columns 0,1 of sTcol are 1.0 (so mu is uniform),
// val array is S0/S1 for m<2 and A for m>=2 -> 8 ds_read_b128 per lane total.
// Epilogue exp0(log0(s)) collapses to y = s if |s| < ATANH_MAX else ATANH_MAX*s/|s|.
__global__ __launch_bounds__(256) void PManifold_kernel(
    const float* __restrict__ inp,    // (B,H,N,2) fp32
    const float* __restrict__ theta,  // (H,K,M)  fp32
    float* __restrict__ out)          // (B,H,K,M) fp32
{
    __shared__ __align__(16) float sTcol[Mm * TS];   // column-major theta; cols 0,1 = 1.0f
    __shared__ __align__(16) float sRed[4][3 * TS];  // per-wave: S0 @0, S1 @TS, A @2*TS

    const int tid  = threadIdx.x;
    const int lane = tid & 63;                  // = theta row k
    const int wav  = tid >> 6;
    const int g    = blockIdx.x * 4 + wav;      // global wave id in [0, B*H*K)
    const int kp   = g & 63;                    // output chart index k'
    const int bh   = g >> 6;                    // b*H + h (uniform within block)
    const int h    = bh & (Hn - 1);

    // ---- stage theta_h column-major into LDS; columns 0,1 become 1.0f ----
    {
        const int r  = tid >> 2;                // row 0..63
        const int cb = (tid & 3) << 2;          // col base 0,4,8,12
        const float4 q = *reinterpret_cast<const float4*>(theta + (size_t)(h * Kk + r) * Mm + cb);
        sTcol[(cb + 0) * TS + r] = (cb == 0) ? 1.0f : q.x;
        sTcol[(cb + 1) * TS + r] = (cb == 0) ? 1.0f : q.y;
        sTcol[(cb + 2) * TS + r] = q.z;
        sTcol[(cb + 3) * TS + r] = q.w;
    }
    __syncthreads();

    // ---- theta row (h, lane) from global (coalesced, L2-hot): t0,t1 and c ----
    float t0, t1, c;
    {
        const float4* tq = reinterpret_cast<const float4*>(theta) + (size_t)(h * Kk + lane) * 4;
        float4 q0 = tq[0], q1 = tq[1], q2 = tq[2], q3 = tq[3];
        t0 = q0.x; t1 = q0.y;
        c  = q0.z * q0.z + q0.w * q0.w;
        c  = fmaf(q1.x, q1.x, fmaf(q1.y, q1.y, fmaf(q1.z, q1.z, fmaf(q1.w, q1.w, c))));
        c  = fmaf(q2.x, q2.x, fmaf(q2.y, q2.y, fmaf(q2.z, q2.z, fmaf(q2.w, q2.w, c))));
        c  = fmaf(q3.x, q3.x, fmaf(q3.y, q3.y, fmaf(q3.z, q3.z, fmaf(q3.w, q3.w, c))));
    }

    // ---- exp0 of the wave's 8 points; lanes 0..7 canonical, readlane broadcast ----
    float E0, E1;
    {
        const int p = lane & 7;
        const float2* ip = reinterpret_cast<const float2*>(inp) + (size_t)bh * Np;
        float2 dd = ip[(p << 6) + kp];          // point n = 64p + k'
        float nd = sqrtf(fmaf(dd.x, dd.x, dd.y * dd.y));
        float nc = fmaxf(nd, EPSf);
        float ex = __expf(2.0f * nc);           // nd <= sqrt(2): no overflow
        // tanh(nc)/nc = (e-1) / ((e+1)*nc) : one rcp instead of two
        float sc = (ex - 1.0f) * __frcp_rn((ex + 1.0f) * nc);
        E0 = sc * dd.x;
        E1 = sc * dd.y;
    }
    float e0[8], e1[8];
    #pragma unroll
    for (int p = 0; p < 8; ++p) {
        e0[p] = __int_as_float(__builtin_amdgcn_readlane(__float_as_int(E0), p));
        e1[p] = __int_as_float(__builtin_amdgcn_readlane(__float_as_int(E1), p));
    }

    // ---- 8 tangent terms for this lane's theta row (3 transcendentals/term) ----
    float At = 0.0f, S0 = 0.0f, S1 = 0.0f;
    #pragma unroll
    for (int p = 0; p < 8; ++p) {
        float x0 = e0[p] + t0;
        float x1 = e1[p] + t1;
        float u  = fmaf(x0, x0, fmaf(x1, x1, c));
        u        = fmaxf(u, 1e-14f);            // => r >= 1e-7 = EPS clamp of reference
        float rs = rsqrtf(u);                   // 1/r
        float rc = fminf(u * rs, MAXN);         // min(r, MAXN)
        float Q  = (1.0f + rc) * __frcp_rn(1.0f - rc);
        float tt = __log2f(Q) * rs;             // atanh(rc)/r = HALF_LN2 * tt
        float a  = HALF_LN2 * tt;
        At += tt;
        S0 = fmaf(a, x0, S0);
        S1 = fmaf(a, x1, S1);
    }
    const float A = HALF_LN2 * At;

    // ---- publish per-k partials ----
    sRed[wav][lane]          = S0;
    sRed[wav][TS + lane]     = S1;
    sRed[wav][2 * TS + lane] = A;
    __syncthreads();

    // ---- vectorized quarter-dot: lane (m = l&15, q = l>>4) ----
    const int m = lane & 15;
    const int q = lane >> 4;
    const float* valArr = &sRed[wav][(m < 2) ? m * TS : 2 * TS];
    const float* muCol  = &sTcol[m * TS];
    float acc = 0.0f;
    #pragma unroll
    for (int jj = 0; jj < 4; ++jj) {
        float4 v4 = *reinterpret_cast<const float4*>(valArr + (q << 4) + (jj << 2));
        float4 u4 = *reinterpret_cast<const float4*>(muCol  + (q << 4) + (jj << 2));
        acc = fmaf(v4.x, u4.x, fmaf(v4.y, u4.y, fmaf(v4.z, u4.z, fmaf(v4.w, u4.w, acc))));
    }
    // combine the 4 quarters -> full component in every lane
    acc += __shfl_xor(acc, 16, 64);
    acc += __shfl_xor(acc, 32, 64);

    // ---- epilogue: y = g(|s|) * s ----
    float w = acc * acc;
    #pragma unroll
    for (int off = 1; off < 16; off <<= 1) w += __shfl_xor(w, off, 64);
    float nn  = fmaxf(sqrtf(w), EPSf);
    float gsc = (nn < ATANH_MAX) ? 1.0f : __fdividef(ATANH_MAX, nn);

    if (lane < 16) {
        out[(size_t)g * Mm + m] = gsc * acc;    // 16 lanes x 4B, coalesced 64B
    }
}

extern "C" void kernel_launch(void* const* d_in, const int* in_sizes, int n_in,
                              void* d_out, int out_size, void* d_ws, size_t ws_size,
                              hipStream_t stream) {
    const float* inp   = (const float*)d_in[0];  // (64,2,512,2) fp32
    const float* theta = (const float*)d_in[1];  // (2,64,16)   fp32
    float*       out   = (float*)d_out;          // (64,2,64,16) fp32

    const int total_waves = Bsz * Hn * Kk;       // 8192
    dim3 grid(total_waves / 4), block(256);
    hipLaunchKernelGGL(PManifold_kernel, grid, block, 0, stream, inp, theta, out);
}

// Round 5
// 59.233 us; speedup vs baseline: 1.0307x; 1.0307x over previous
//
#include <hip/hip_runtime.h>

// Problem config (fixed by reference): B=64, H=2, N=512, K=64, M=16
constexpr int Bsz = 64;
constexpr int Hn  = 2;
constexpr int Np  = 512;
constexpr int Kk  = 64;
constexpr int Mm  = 16;

constexpr int TS = 68;   // column stride in LDS (16B-aligned, bank-staggered)

#define EPSf      1e-7f
#define MAXN      (1.0f - 1e-5f)
#define ATANH_MAX 6.1030338f     // atanh(1 - 1e-5)
#define HALF_LN2  0.34657359f    // 0.5 * ln(2)

__device__ __forceinline__ float fast_rcp(float x) { return __builtin_amdgcn_rcpf(x); }

// Index identity (reference's raw reshape (B,K*N,M)->(B,N,K,M)):
//   out[b,h,k'] = epilogue( sum_{k<64} sum_{p<8} tangent(point n=64p+k', theta row k) )
// Per-term (x = exp0(pad(dgm)) + theta_k, only 2 nonzero exp0 comps):
//   u = x0^2+x1^2+c_k, rs = rsqrt(u), r = u*rs, a = atanh(min(r,MAXN))*rs
//   per-lane(k) partial over p: (S0,S1,A); component m>=2 of sum = sum_k A_k*t[k][m].
// This version: ONE WAVE HANDLES TWO OUTPUTS (k' and k'+32) sharing theta row, c,
// staging, barriers; the dot phase reuses each theta-column ds_read for both outputs.
// Epilogue exp0(log0(s)) collapses to y = s if |s| < ATANH_MAX else ATANH_MAX*s/|s|.
__global__ __launch_bounds__(256) void PManifold_kernel(
    const float* __restrict__ inp,    // (B,H,N,2) fp32
    const float* __restrict__ theta,  // (H,K,M)  fp32
    float* __restrict__ out)          // (B,H,K,M) fp32
{
    __shared__ __align__(16) float sTcol[Mm * TS];   // column-major theta; cols 0,1 = 1.0f
    __shared__ __align__(16) float sRed[4][6 * TS];  // per-wave: S0a,S1a,Aa,S0b,S1b,Ab

    const int tid  = threadIdx.x;
    const int lane = tid & 63;                  // = theta row k
    const int wav  = tid >> 6;
    const int g    = blockIdx.x * 4 + wav;      // wave id in [0, B*H*K/2) = [0,4096)
    const int kp   = g & 31;                    // output pair: k' = kp and kp+32
    const int bh   = g >> 5;                    // b*H + h (uniform within block)
    const int h    = bh & (Hn - 1);

    // ---- stage theta_h column-major into LDS; columns 0,1 become 1.0f ----
    {
        const int r  = tid >> 2;                // row 0..63
        const int cb = (tid & 3) << 2;          // col base 0,4,8,12
        const float4 q = *reinterpret_cast<const float4*>(theta + (size_t)(h * Kk + r) * Mm + cb);
        sTcol[(cb + 0) * TS + r] = (cb == 0) ? 1.0f : q.x;
        sTcol[(cb + 1) * TS + r] = (cb == 0) ? 1.0f : q.y;
        sTcol[(cb + 2) * TS + r] = q.z;
        sTcol[(cb + 3) * TS + r] = q.w;
    }
    __syncthreads();

    // ---- theta row (h, lane) from global (coalesced, L2-hot): t0,t1 and c ----
    float t0, t1, c;
    {
        const float4* tq = reinterpret_cast<const float4*>(theta) + (size_t)(h * Kk + lane) * 4;
        float4 q0 = tq[0], q1 = tq[1], q2 = tq[2], q3 = tq[3];
        t0 = q0.x; t1 = q0.y;
        c  = q0.z * q0.z + q0.w * q0.w;
        c  = fmaf(q1.x, q1.x, fmaf(q1.y, q1.y, fmaf(q1.z, q1.z, fmaf(q1.w, q1.w, c))));
        c  = fmaf(q2.x, q2.x, fmaf(q2.y, q2.y, fmaf(q2.z, q2.z, fmaf(q2.w, q2.w, c))));
        c  = fmaf(q3.x, q3.x, fmaf(q3.y, q3.y, fmaf(q3.z, q3.z, fmaf(q3.w, q3.w, c))));
    }

    // ---- exp0 of the wave's 16 points (8 per output); lanes 0..15 canonical ----
    float E0, E1;
    {
        const int pp  = lane & 15;              // 0..7 -> output a, 8..15 -> output b
        const int idx = ((pp & 7) << 6) + kp + ((pp >> 3) << 5);  // n = 64p + k'(+32)
        const float2* ip = reinterpret_cast<const float2*>(inp) + (size_t)bh * Np;
        float2 dd = ip[idx];
        float nd = sqrtf(fmaf(dd.x, dd.x, dd.y * dd.y));
        float nc = fmaxf(nd, EPSf);
        float ex = __expf(2.0f * nc);           // nd <= sqrt(2): no overflow
        // tanh(nc)/nc = (e-1) / ((e+1)*nc) : single v_rcp_f32
        float sc = (ex - 1.0f) * fast_rcp((ex + 1.0f) * nc);
        E0 = sc * dd.x;
        E1 = sc * dd.y;
    }
    float e0[16], e1[16];
    #pragma unroll
    for (int p = 0; p < 16; ++p) {
        e0[p] = __int_as_float(__builtin_amdgcn_readlane(__float_as_int(E0), p));
        e1[p] = __int_as_float(__builtin_amdgcn_readlane(__float_as_int(E1), p));
    }

    // ---- 16 tangent terms (8 per output) for this lane's theta row ----
    float Aa = 0.0f, S0a = 0.0f, S1a = 0.0f;
    float Ab = 0.0f, S0b = 0.0f, S1b = 0.0f;
    #pragma unroll
    for (int p = 0; p < 16; ++p) {
        float x0 = e0[p] + t0;
        float x1 = e1[p] + t1;
        float u  = fmaf(x0, x0, fmaf(x1, x1, c));
        u        = fmaxf(u, 1e-14f);            // => r >= 1e-7 = EPS clamp of reference
        float rs = rsqrtf(u);                   // 1/r
        float rc = fminf(u * rs, MAXN);         // min(r, MAXN)
        float Q  = (1.0f + rc) * fast_rcp(1.0f - rc);
        float tt = __log2f(Q) * rs;             // atanh(rc)/r = HALF_LN2 * tt
        float a  = HALF_LN2 * tt;
        if (p < 8) { Aa += tt; S0a = fmaf(a, x0, S0a); S1a = fmaf(a, x1, S1a); }
        else       { Ab += tt; S0b = fmaf(a, x0, S0b); S1b = fmaf(a, x1, S1b); }
    }

    // ---- publish per-k partials for both outputs ----
    sRed[wav][0 * TS + lane] = S0a;
    sRed[wav][1 * TS + lane] = S1a;
    sRed[wav][2 * TS + lane] = HALF_LN2 * Aa;
    sRed[wav][3 * TS + lane] = S0b;
    sRed[wav][4 * TS + lane] = S1b;
    sRed[wav][5 * TS + lane] = HALF_LN2 * Ab;
    __syncthreads();

    // ---- vectorized quarter-dot: lane (m = l&15, q = l>>4); theta column shared ----
    const int m = lane & 15;
    const int q = lane >> 4;
    const int voff = (m < 2) ? m * TS : 2 * TS;
    const float* valA  = &sRed[wav][voff];
    const float* valB  = &sRed[wav][3 * TS + voff];
    const float* muCol = &sTcol[m * TS];
    float accA = 0.0f, accB = 0.0f;
    #pragma unroll
    for (int jj = 0; jj < 4; ++jj) {
        const int o = (q << 4) + (jj << 2);
        float4 u4 = *reinterpret_cast<const float4*>(muCol + o);   // read once, use twice
        float4 va = *reinterpret_cast<const float4*>(valA + o);
        float4 vb = *reinterpret_cast<const float4*>(valB + o);
        accA = fmaf(va.x, u4.x, fmaf(va.y, u4.y, fmaf(va.z, u4.z, fmaf(va.w, u4.w, accA))));
        accB = fmaf(vb.x, u4.x, fmaf(vb.y, u4.y, fmaf(vb.z, u4.z, fmaf(vb.w, u4.w, accB))));
    }
    accA += __shfl_xor(accA, 16, 64);
    accA += __shfl_xor(accA, 32, 64);
    accB += __shfl_xor(accB, 16, 64);
    accB += __shfl_xor(accB, 32, 64);

    // ---- epilogue per output: y = g(|s|) * s ----
    float wA = accA * accA, wB = accB * accB;
    #pragma unroll
    for (int off = 1; off < 16; off <<= 1) {
        wA += __shfl_xor(wA, off, 64);
        wB += __shfl_xor(wB, off, 64);
    }
    float nnA  = fmaxf(sqrtf(wA), EPSf);
    float nnB  = fmaxf(sqrtf(wB), EPSf);
    float gA = (nnA < ATANH_MAX) ? 1.0f : __fdividef(ATANH_MAX, nnA);
    float gB = (nnB < ATANH_MAX) ? 1.0f : __fdividef(ATANH_MAX, nnB);

    // lanes 0-15 write output (bh,kp); lanes 16-31 write (bh,kp+32)
    if (lane < 32) {
        const int    which = lane >> 4;                       // 0 -> a, 1 -> b
        const size_t row   = (size_t)(bh * Kk + kp + (which << 5));
        const float  val   = which ? (gB * accB) : (gA * accA);
        out[row * Mm + m] = val;
    }
}

extern "C" void kernel_launch(void* const* d_in, const int* in_sizes, int n_in,
                              void* d_out, int out_size, void* d_ws, size_t ws_size,
                              hipStream_t stream) {
    const float* inp   = (const float*)d_in[0];  // (64,2,512,2) fp32
    const float* theta = (const float*)d_in[1];  // (2,64,16)   fp32
    float*       out   = (float*)d_out;          // (64,2,64,16) fp32

    const int total_waves = Bsz * Hn * Kk / 2;   // 4096 (two outputs per wave)
    dim3 grid(total_waves / 4), block(256);
    hipLaunchKernelGGL(PManifold_kernel, grid, block, 0, stream, inp, theta, out);
}